// Round 10
// baseline (67.504 us; speedup 1.0000x reference)
//
#include <hip/hip_runtime.h>
#include <hip/hip_bf16.h>

// out[m,u] = sum_t x[m,t] * W_eff[u,t] + b_eff[u]      (m = 32*512 rows)
//   W_eff = Ws + (Wt - Ws) @ A   (A = causal window-mean, window 25)
// Round-10: r6/r8 skeleton (x-tile in LDS, ONE barrier, W global->reg,
// zero-barrier K-loop) resized for 2 RESIDENT BLOCKS/CU to overlap phases:
// BM=32, 512 thr / 8 waves, wave = 32m x 96u -> acc 2x6 = 48 AGPR (<=64),
// W single-buffered JIT (arch VGPR ~57 <= 64), LDS 47.6 KB (2 blocks fit).
// launch_bounds(512,4): 16 waves/CU, 64-arch/64-acc split (r7 evidence).

#define Tdim  720
#define KP    736      // padded K (23*32); Wb zero-filled for k>=720
#define WROWS 768      // padded u-rows of Wb (zero rows >=720)
#define NK    23
#define BM    32       // m-rows per block (32*744*2B = 47616 B LDS)
#define APAD  744      // LDS row stride in elems (2-way bank alias, free per m136)

using bf16x8 = __attribute__((ext_vector_type(8))) __bf16;
using f32x4  = __attribute__((ext_vector_type(4))) float;

__global__ void fold_w_kernel(const float* __restrict__ tw,
                              const float* __restrict__ tb,
                              const float* __restrict__ sw,
                              const float* __restrict__ sb,
                              __bf16* __restrict__ Wb,
                              float* __restrict__ beff) {
  int idx = blockIdx.x * 256 + threadIdx.x;
  if (idx >= WROWS * KP) return;
  int u = idx / KP;
  int i = idx - u * KP;
  float w = 0.0f;
  if (u < Tdim && i < Tdim) {
    const float* twr = tw + (size_t)u * Tdim;
    const float* swr = sw + (size_t)u * Tdim;
    int tend = (i + 25 < Tdim) ? (i + 25) : Tdim;
    float acc = 0.0f;
    if (i >= 24) {
      #pragma unroll 5
      for (int t = i; t < tend; ++t) acc += twr[t] - swr[t];
      acc *= 0.04f;
    } else {
      for (int t = i; t < tend; ++t) {
        float c = (t >= 24) ? 0.04f : 1.0f / (float)(t + 1);
        acc += (twr[t] - swr[t]) * c;
      }
    }
    w = swr[i] + acc;
  }
  Wb[idx] = (__bf16)w;
  if (i == 0 && u < Tdim) beff[u] = tb[u] + sb[u];
}

__global__ __launch_bounds__(512, 4)
void dlinear_gemm(const float* __restrict__ x,
                  const __bf16* __restrict__ Wb,
                  const float* __restrict__ beff,
                  float* __restrict__ out) {
  __shared__ __bf16 As[BM * APAD];   // 47616 B -> 2 blocks/CU

  const int tid  = threadIdx.x;
  const int lane = tid & 63;
  const int wid  = tid >> 6;          // 0..7
  const int lg = lane >> 4, lr = lane & 15;

  const int m0 = blockIdx.x * BM;
  const int u0 = wid * 96;            // wave owns 96 u-cols (768 = 8*96 padded)

  // ---- prologue: x[m0..m0+32) x [0..720) -> LDS bf16 (coalesced 32B/lane)
  #pragma unroll
  for (int c = 0; c < 6; ++c) {
    int idx = tid + 512 * c;          // 8-f32 chunk id; 90 chunks/row, 2880 total
    if (idx < BM * 90) {
      int row  = idx / 90;
      int col8 = idx - row * 90;
      const float* p = x + (size_t)(m0 + row) * Tdim + col8 * 8;
      f32x4 a0 = ((const f32x4*)p)[0];
      f32x4 a1 = ((const f32x4*)p)[1];
      bf16x8 v;
      #pragma unroll
      for (int j = 0; j < 4; ++j) { v[j] = (__bf16)a0[j]; v[j + 4] = (__bf16)a1[j]; }
      *(bf16x8*)(&As[row * APAD + col8 * 8]) = v;
    }
  }
  {  // zero the K-pad [720,736): 32 rows x 16 elems = 512 threads exactly
    int r = tid >> 4;
    int c = 720 + (tid & 15);
    As[r * APAD + c] = (__bf16)0.0f;
  }
  __syncthreads();                    // the ONLY barrier

  // ---- W base pointers: frag ni -> row u0+ni*16+lr, 16B chunk lg; t*64B folds
  const __bf16* wp[6];
  #pragma unroll
  for (int ni = 0; ni < 6; ++ni)
    wp[ni] = Wb + (size_t)(u0 + ni * 16 + lr) * KP + lg * 8;

  int arofs[2];
  #pragma unroll
  for (int mi = 0; mi < 2; ++mi) arofs[mi] = (mi * 16 + lr) * APAD + lg * 8;

  f32x4 acc[2][6];
  #pragma unroll
  for (int mi = 0; mi < 2; ++mi)
    #pragma unroll
    for (int ni = 0; ni < 6; ++ni) {
      f32x4 z; z[0] = 0.f; z[1] = 0.f; z[2] = 0.f; z[3] = 0.f;
      acc[mi][ni] = z;
    }

  // ---- K-loop: W JIT single-buffer (fits 64-arch cap), zero barriers
  for (int t = 0; t < NK; ++t) {
    bf16x8 bv[6];
    #pragma unroll
    for (int ni = 0; ni < 6; ++ni) bv[ni] = *(const bf16x8*)(wp[ni] + t * 32);
    bf16x8 av[2];
    #pragma unroll
    for (int mi = 0; mi < 2; ++mi) av[mi] = *(const bf16x8*)(&As[arofs[mi] + t * 32]);
    #pragma unroll
    for (int mi = 0; mi < 2; ++mi)
      #pragma unroll
      for (int ni = 0; ni < 6; ++ni)
        acc[mi][ni] = __builtin_amdgcn_mfma_f32_16x16x32_bf16(av[mi], bv[ni],
                                                              acc[mi][ni], 0, 0, 0);
  }

  // ---- epilogue: C/D layout col = lr -> u, row = lg*4 + j -> m
  #pragma unroll
  for (int ni = 0; ni < 6; ++ni) {
    const int u = u0 + ni * 16 + lr;
    if (u >= Tdim) continue;
    const float bias = beff[u];
    #pragma unroll
    for (int mi = 0; mi < 2; ++mi) {
      const int mb = m0 + mi * 16 + lg * 4;
      #pragma unroll
      for (int j = 0; j < 4; ++j)
        out[(size_t)(mb + j) * Tdim + u] = acc[mi][ni][j] + bias;
    }
  }
}

extern "C" void kernel_launch(void* const* d_in, const int* in_sizes, int n_in,
                              void* d_out, int out_size, void* d_ws, size_t ws_size,
                              hipStream_t stream) {
  const float* x  = (const float*)d_in[0];
  const float* tw = (const float*)d_in[1];
  const float* tb = (const float*)d_in[2];
  const float* sw = (const float*)d_in[3];
  const float* sb = (const float*)d_in[4];
  float* out = (float*)d_out;

  __bf16* Wb  = (__bf16*)d_ws;
  float* beff = (float*)((char*)d_ws + (size_t)WROWS * KP * sizeof(__bf16));

  const int fold_total = WROWS * KP;
  fold_w_kernel<<<dim3((fold_total + 255) / 256), dim3(256), 0, stream>>>(
      tw, tb, sw, sb, Wb, beff);

  const int M = in_sizes[0] / Tdim;            // 16384
  dim3 grid(M / BM);                           // 512 blocks, 2 per CU
  dlinear_gemm<<<grid, dim3(512), 0, stream>>>(x, Wb, beff, out);
}

// Round 11
// 46.753 us; speedup vs baseline: 1.4438x; 1.4438x over previous
//
#include <hip/hip_runtime.h>
#include <hip/hip_bf16.h>

// out[m,u] = sum_t x[m,t] * W_eff[u,t] + b_eff[u]      (m = 32*512 rows)
//   W_eff = Ws + (Wt - Ws) @ A   (A = causal window-mean, window 25)
// Round-11: r8 skeleton (x-tile in LDS, ONE barrier, 1024 thr / 16 waves,
// 1 block/CU, wave = 64m x 48u, zero-barrier K-loop) with the W register
// pipeline deepened to DEPTH-2 (3-slot named ring, static indices):
// W(t) is issued 2 iterations before use -> ~480 cy coverage > L2 latency.
// Register budget: ~64 arch + 48 acc = 112 <= 128 cap (16 waves/block).

#define Tdim  720
#define KP    736      // padded K (23*32); Wb zero-filled for k>=720
#define WROWS 768      // padded u-rows of Wb (zero rows >=720)
#define NK    23
#define BM    64       // m-rows per block
#define APAD  744      // LDS row stride in elems (2-way bank alias, free per m136)

using bf16x8 = __attribute__((ext_vector_type(8))) __bf16;
using f32x4  = __attribute__((ext_vector_type(4))) float;

__global__ void fold_w_kernel(const float* __restrict__ tw,
                              const float* __restrict__ tb,
                              const float* __restrict__ sw,
                              const float* __restrict__ sb,
                              __bf16* __restrict__ Wb,
                              float* __restrict__ beff) {
  int idx = blockIdx.x * 256 + threadIdx.x;
  if (idx >= WROWS * KP) return;
  int u = idx / KP;
  int i = idx - u * KP;
  float w = 0.0f;
  if (u < Tdim && i < Tdim) {
    const float* twr = tw + (size_t)u * Tdim;
    const float* swr = sw + (size_t)u * Tdim;
    int tend = (i + 25 < Tdim) ? (i + 25) : Tdim;
    float acc = 0.0f;
    if (i >= 24) {
      #pragma unroll 5
      for (int t = i; t < tend; ++t) acc += twr[t] - swr[t];
      acc *= 0.04f;
    } else {
      for (int t = i; t < tend; ++t) {
        float c = (t >= 24) ? 0.04f : 1.0f / (float)(t + 1);
        acc += (twr[t] - swr[t]) * c;
      }
    }
    w = swr[i] + acc;
  }
  Wb[idx] = (__bf16)w;
  if (i == 0 && u < Tdim) beff[u] = tb[u] + sb[u];
}

__global__ __launch_bounds__(1024, 1)
void dlinear_gemm(const float* __restrict__ x,
                  const __bf16* __restrict__ Wb,
                  const float* __restrict__ beff,
                  float* __restrict__ out) {
  __shared__ __bf16 As[BM * APAD];   // 95232 B -> 1 block/CU

  const int tid  = threadIdx.x;
  const int lane = tid & 63;
  const int wid  = tid >> 6;          // 0..15
  const int lg = lane >> 4, lr = lane & 15;

  const int m0 = blockIdx.x * BM;
  const int u0 = wid * 48;            // wave owns 48 u-cols (768 = 16*48 padded)

  // ---- prologue: x[m0..m0+64) x [0..720) -> LDS bf16 (coalesced 32B/lane)
  #pragma unroll
  for (int c = 0; c < 6; ++c) {
    int idx = tid + 1024 * c;         // 8-f32 chunk id; 90 chunks per row
    if (idx < BM * 90) {
      int row  = idx / 90;
      int col8 = idx - row * 90;
      const float* p = x + (size_t)(m0 + row) * Tdim + col8 * 8;
      f32x4 a0 = ((const f32x4*)p)[0];
      f32x4 a1 = ((const f32x4*)p)[1];
      bf16x8 v;
      #pragma unroll
      for (int j = 0; j < 4; ++j) { v[j] = (__bf16)a0[j]; v[j + 4] = (__bf16)a1[j]; }
      *(bf16x8*)(&As[row * APAD + col8 * 8]) = v;
    }
  }
  {  // zero the K-pad [720,736): 64 rows x 16 elems = 1024 threads exactly
    int r = tid >> 4;
    int c = 720 + (tid & 15);
    As[r * APAD + c] = (__bf16)0.0f;
  }
  __syncthreads();                    // the ONLY barrier

  // ---- W stream pointers: frag ni -> row u0+ni*16+lr, 16B chunk lg within K-step
  const __bf16* wp[3];
  #pragma unroll
  for (int ni = 0; ni < 3; ++ni)
    wp[ni] = Wb + (size_t)(u0 + ni * 16 + lr) * KP + lg * 8;

  int arofs[4];
  #pragma unroll
  for (int mi = 0; mi < 4; ++mi) arofs[mi] = (mi * 16 + lr) * APAD + lg * 8;

  f32x4 acc[4][3];
  #pragma unroll
  for (int mi = 0; mi < 4; ++mi)
    #pragma unroll
    for (int ni = 0; ni < 3; ++ni) {
      f32x4 z; z[0] = 0.f; z[1] = 0.f; z[2] = 0.f; z[3] = 0.f;
      acc[mi][ni] = z;
    }

  // ---- K-loop: depth-2 W pipeline, 3 named slots, zero barriers.
  // slot s[t%3] holds W(t); issue W(t+2) into s[(t+2)%3] at step t.
  bf16x8 s0[3], s1[3], s2[3];
  #pragma unroll
  for (int ni = 0; ni < 3; ++ni) s0[ni] = *(const bf16x8*)(wp[ni]);        // W0
  #pragma unroll
  for (int ni = 0; ni < 3; ++ni) s1[ni] = *(const bf16x8*)(wp[ni] + 32);   // W1

#define GEMM_STEP(T, SLOT, ISSUE_SLOT, DO_ISSUE)                               \
  {                                                                            \
    if (DO_ISSUE) {                                                            \
      _Pragma("unroll")                                                        \
      for (int ni = 0; ni < 3; ++ni)                                           \
        ISSUE_SLOT[ni] = *(const bf16x8*)(wp[ni] + ((T) + 2) * 32);            \
    }                                                                          \
    bf16x8 av[4];                                                              \
    _Pragma("unroll")                                                          \
    for (int mi = 0; mi < 4; ++mi)                                             \
      av[mi] = *(const bf16x8*)(&As[arofs[mi] + (T) * 32]);                    \
    _Pragma("unroll")                                                          \
    for (int mi = 0; mi < 4; ++mi)                                             \
      _Pragma("unroll")                                                        \
      for (int ni = 0; ni < 3; ++ni)                                           \
        acc[mi][ni] = __builtin_amdgcn_mfma_f32_16x16x32_bf16(av[mi],          \
                        SLOT[ni], acc[mi][ni], 0, 0, 0);                       \
  }

  for (int t = 0; t < 21; t += 3) {    // t = 0,3,...,18 (7 triples, covers 0..20)
    GEMM_STEP(t,     s0, s2, true)     // compute W(t),   issue W(t+2) -> s2
    GEMM_STEP(t + 1, s1, s0, true)     // compute W(t+1), issue W(t+3) -> s0
    GEMM_STEP(t + 2, s2, s1, true)     // compute W(t+2), issue W(t+4) -> s1
  }
  GEMM_STEP(21, s0, s2, false)         // W21 (loaded at t=18 phase b)
  GEMM_STEP(22, s1, s2, false)         // W22 (loaded at t=18 phase c)
#undef GEMM_STEP

  // ---- epilogue: C/D layout col = lr -> u, row = lg*4 + j -> m
  #pragma unroll
  for (int ni = 0; ni < 3; ++ni) {
    const int u = u0 + ni * 16 + lr;
    if (u >= Tdim) continue;
    const float bias = beff[u];
    #pragma unroll
    for (int mi = 0; mi < 4; ++mi) {
      const int mb = m0 + mi * 16 + lg * 4;
      #pragma unroll
      for (int j = 0; j < 4; ++j)
        out[(size_t)(mb + j) * Tdim + u] = acc[mi][ni][j] + bias;
    }
  }
}

extern "C" void kernel_launch(void* const* d_in, const int* in_sizes, int n_in,
                              void* d_out, int out_size, void* d_ws, size_t ws_size,
                              hipStream_t stream) {
  const float* x  = (const float*)d_in[0];
  const float* tw = (const float*)d_in[1];
  const float* tb = (const float*)d_in[2];
  const float* sw = (const float*)d_in[3];
  const float* sb = (const float*)d_in[4];
  float* out = (float*)d_out;

  __bf16* Wb  = (__bf16*)d_ws;
  float* beff = (float*)((char*)d_ws + (size_t)WROWS * KP * sizeof(__bf16));

  const int fold_total = WROWS * KP;
  fold_w_kernel<<<dim3((fold_total + 255) / 256), dim3(256), 0, stream>>>(
      tw, tb, sw, sb, Wb, beff);

  const int M = in_sizes[0] / Tdim;            // 16384
  dim3 grid(M / BM);                           // 256 blocks, 1 per CU
  dlinear_gemm<<<grid, dim3(1024), 0, stream>>>(x, Wb, beff, out);
}